// Round 8
// baseline (166.484 us; speedup 1.0000x reference)
//
#include <hip/hip_runtime.h>
#include <hip/hip_bf16.h>
#include <stdint.h>

#define B_  2
#define S_  2048
#define D_  1024
#define H_  16
#define HD_ 64

typedef __attribute__((ext_vector_type(8)))  __bf16 bf16x8;
typedef __attribute__((ext_vector_type(4)))  __bf16 bf16x4;
typedef __attribute__((ext_vector_type(4)))  short  s16x4;
typedef __attribute__((ext_vector_type(8)))  short  s16x8;
typedef __attribute__((ext_vector_type(2)))  float  f32x2;
typedef __attribute__((ext_vector_type(4)))  float  f32x4;
typedef __attribute__((ext_vector_type(16))) float  f32x16;
typedef __attribute__((ext_vector_type(4)))  uint32_t u32x4;

// 0.125 * log2(e): folded into Q so attention scores feed exp2 directly.
#define QSCALE 0.18033688011112042f

__device__ __forceinline__ void gload16(const void* g, void* l) {
  __builtin_amdgcn_global_load_lds(
      (__attribute__((address_space(1))) void*)(uintptr_t)g,
      (__attribute__((address_space(3))) void*)(uintptr_t)l,
      16, 0, 0);
}

// concat two K=8 fragments into one K=16 operand (same (half,elem)->k map on
// both A and B sides). Harness-verified in R1/R2.
__device__ __forceinline__ bf16x8 cat8(s16x4 a, s16x4 b) {
  return __builtin_bit_cast(
      bf16x8, (s16x8)__builtin_shufflevector(a, b, 0, 1, 2, 3, 4, 5, 6, 7));
}

// NOTE (R4 post-mortem): v_cvt_pk_bf16_f32 packing FAILED accuracy (biased
// rounding vs the f32 lsum). Keep the +0x8000+v_perm round-half-up pack.
// NOTE (R6 post-mortem): fused butterfly/atomic epilogue failed accuracy;
// partial-output po/pl + attn2 is the proven path - kept verbatim here.

// ---------------- fused prep: zero out / convert X / transpose W ----------------
__global__ __launch_bounds__(256) void prep(
    const float* __restrict__ x, const float* __restrict__ wq,
    const float* __restrict__ wk, const float* __restrict__ wv,
    __bf16* __restrict__ xb, __bf16* __restrict__ wt, float* __restrict__ out) {
  __shared__ float tile[32][33];
  const int t = threadIdx.x;
  const int bx = blockIdx.x;
  if (bx < 4096) {
    int i = bx * 256 + t;
    float4 v = ((const float4*)x)[i];
    bf16x4 o;
    o[0] = (__bf16)v.x; o[1] = (__bf16)v.y; o[2] = (__bf16)v.z; o[3] = (__bf16)v.w;
    ((bf16x4*)xb)[i] = o;
  } else if (bx < 7168) {
    int tb = bx - 4096;
    int z = tb >> 10;
    int rem = tb & 1023;
    int n0 = (rem & 31) * 32, k0 = (rem >> 5) * 32;
    const float* w = (z == 0) ? wq : (z == 1 ? wk : wv);
    __bf16* o = wt + (size_t)z * D_ * D_;
    int tx = t & 31, ty = t >> 5;
    for (int i = 0; i < 4; ++i)
      tile[ty + 8 * i][tx] = w[(size_t)(k0 + ty + 8 * i) * D_ + n0 + tx];
    __syncthreads();
    for (int i = 0; i < 4; ++i)
      o[(size_t)(n0 + ty + 8 * i) * D_ + k0 + tx] = (__bf16)tile[tx][ty + 8 * i];
  } else {
    float4* o4 = (float4*)out;
    float4 z4 = {0.f, 0.f, 0.f, 0.f};
    o4[t] = z4;
    o4[t + 256] = z4;
  }
}

// ---------------- QKV GEMM, 128x128, BK=32, dbuf (unchanged) ----------------
__global__ __launch_bounds__(256, 3) void gemm_qkv(
    const __bf16* __restrict__ xb, const __bf16* __restrict__ wt,
    const float* __restrict__ bq, const float* __restrict__ bk,
    const float* __restrict__ bv, __bf16* __restrict__ qh,
    __bf16* __restrict__ kh, __bf16* __restrict__ vt) {
  constexpr int K = 1024;
  constexpr int NIT = K / 32;
  __shared__ __attribute__((aligned(16))) __bf16 lA[2][128 * 32];
  __shared__ __attribute__((aligned(16))) __bf16 lB[2][128 * 32];

  const int z = blockIdx.z;
  const __bf16* w = wt + (size_t)z * K * D_;
  const float* bias = (z == 0) ? bq : (z == 1 ? bk : bv);
  const int t = threadIdx.x;
  const int lane = t & 63;
  const int wid = t >> 6;
  const int quad = lane >> 4;
  const int col = lane & 15;
  const int m0 = blockIdx.x * 128;
  const int n0 = blockIdx.y * 128;
  const int wr = (wid >> 1) * 64;
  const int wc = (wid & 1) * 64;

  const int sr0 = t >> 2;
  const int gc = (t & 3) ^ ((t >> 2) & 3);

  auto stage = [&](int kt, int buf) {
    gload16(xb + (size_t)(m0 + sr0) * K + kt * 32 + gc * 8,
            (char*)&lA[buf][0] + t * 16);
    gload16(xb + (size_t)(m0 + 64 + sr0) * K + kt * 32 + gc * 8,
            (char*)&lA[buf][0] + 4096 + t * 16);
    gload16(w + (size_t)(n0 + sr0) * K + kt * 32 + gc * 8,
            (char*)&lB[buf][0] + t * 16);
    gload16(w + (size_t)(n0 + 64 + sr0) * K + kt * 32 + gc * 8,
            (char*)&lB[buf][0] + 4096 + t * 16);
  };

  f32x4 acc[4][4] = {};

  stage(0, 0);

  if (z < 2) {
    for (int kt = 0; kt < NIT; ++kt) {
      const int cur = kt & 1;
      __syncthreads();
      if (kt + 1 < NIT) stage(kt + 1, cur ^ 1);
      bf16x8 fw[4], fx[4];
      for (int i = 0; i < 4; ++i) {
        int n = wr + i * 16 + col;
        int sl = quad ^ (n & 3);
        fw[i] = *(const bf16x8*)((const char*)&lB[cur][0] + n * 64 + sl * 16);
      }
      for (int j = 0; j < 4; ++j) {
        int m = wc + j * 16 + col;
        int sl = quad ^ (m & 3);
        fx[j] = *(const bf16x8*)((const char*)&lA[cur][0] + m * 64 + sl * 16);
      }
      for (int i = 0; i < 4; ++i)
        for (int j = 0; j < 4; ++j)
          acc[i][j] = __builtin_amdgcn_mfma_f32_16x16x32_bf16(
              fw[i], fx[j], acc[i][j], 0, 0, 0);
    }
    const float scale = (z == 0) ? QSCALE : 1.0f;
    __bf16* dst = (z == 0) ? qh : kh;
    for (int i = 0; i < 4; ++i) {
      int gnb = n0 + wr + i * 16 + quad * 4;
      float4 bi = *(const float4*)(bias + gnb);
      int h = gnb >> 6, hd = gnb & 63;
      for (int j = 0; j < 4; ++j) {
        int gm = m0 + wc + j * 16 + col;
        int b = gm >> 11, s = gm & 2047;
        bf16x4 pk;
        pk[0] = (__bf16)((acc[i][j][0] + bi.x) * scale);
        pk[1] = (__bf16)((acc[i][j][1] + bi.y) * scale);
        pk[2] = (__bf16)((acc[i][j][2] + bi.z) * scale);
        pk[3] = (__bf16)((acc[i][j][3] + bi.w) * scale);
        *(bf16x4*)(dst + ((size_t)(b * H_ + h) * S_ + s) * HD_ + hd) = pk;
      }
    }
  } else {
    for (int kt = 0; kt < NIT; ++kt) {
      const int cur = kt & 1;
      __syncthreads();
      if (kt + 1 < NIT) stage(kt + 1, cur ^ 1);
      bf16x8 fx[4], fw[4];
      for (int i = 0; i < 4; ++i) {
        int m = wr + i * 16 + col;
        int sl = quad ^ (m & 3);
        fx[i] = *(const bf16x8*)((const char*)&lA[cur][0] + m * 64 + sl * 16);
      }
      for (int j = 0; j < 4; ++j) {
        int n = wc + j * 16 + col;
        int sl = quad ^ (n & 3);
        fw[j] = *(const bf16x8*)((const char*)&lB[cur][0] + n * 64 + sl * 16);
      }
      for (int i = 0; i < 4; ++i)
        for (int j = 0; j < 4; ++j)
          acc[i][j] = __builtin_amdgcn_mfma_f32_16x16x32_bf16(
              fx[i], fw[j], acc[i][j], 0, 0, 0);
    }
    for (int i = 0; i < 4; ++i) {
      int gmb = m0 + wr + i * 16 + quad * 4;
      int b = gmb >> 11, s = gmb & 2047;
      for (int j = 0; j < 4; ++j) {
        int gn = n0 + wc + j * 16 + col;
        int h = gn >> 6, hd = gn & 63;
        float bi = bias[gn];
        bf16x4 pk;
        pk[0] = (__bf16)(acc[i][j][0] + bi);
        pk[1] = (__bf16)(acc[i][j][1] + bi);
        pk[2] = (__bf16)(acc[i][j][2] + bi);
        pk[3] = (__bf16)(acc[i][j][3] + bi);
        *(bf16x4*)(vt + ((size_t)(b * H_ + h) * HD_ + hd) * S_ + s) = pk;
      }
    }
  }
}

// ---------------- attention phase 1: 32 q/wave, 4 waves/SIMD ----------------
// grid (bh=32, qblk=16, kc=2) = 1024 blocks = 4/CU = ONE clean generation.
// R8 theory (R2/R3/R5/R7 all neutral -> within-wave restructures exhausted):
// one 32x32x16 MFMA occupies its SIMD matrix pipe ~32 cyc (the "8 cyc" table
// number is per-CU); R2's MfmaUtil 27% + VALUBusy 38% with only 2 waves/SIMD
// means ~35% dead time from unfillable dependency chains. Occupancy steps are
// 128->4 waves, 256->2 waves (m69); the only jump is fitting 128 unified regs.
// This kernel is R2 with the qt dimension DELETED (32 q-rows/wave) and
// serial-st (no bulk hoisting - TLP covers LDS latency now):
// persistent ~52 regs (aq8 + o32 AGPR + ls/ptrs), transient peak ~60 -> ~115.
// __launch_bounds__(256,4) enforces the 128-reg budget -> 4 waves/SIMD.
// TRIPWIRE: FETCH_SIZE >> 12.3 MB = spilling (R1 signature) -> revert to (256,2).
// po/pl/attn2 epilogue kept verbatim from R2 (proven; R6's fused one failed).
__global__ __launch_bounds__(256, 4) void attn1(
    const __bf16* __restrict__ qh, const __bf16* __restrict__ kh,
    const __bf16* __restrict__ vt, __bf16* __restrict__ po,
    float* __restrict__ pl) {
  __shared__ __attribute__((aligned(16))) __bf16 lK[2][64 * 64];  // [sk][hd] swz
  __shared__ __attribute__((aligned(16))) __bf16 lV[2][64 * 64];  // [hd][sk] swz

  const int t = threadIdx.x;
  const int lane = t & 63;
  const int half = lane >> 5;
  const int q31 = lane & 31;
  const int bh = blockIdx.x;
  const int kc = blockIdx.z;
  const int q0w = blockIdx.y * 128 + (t >> 6) * 32;  // wave's 32 q rows

  const __bf16* qbase = qh + (size_t)bh * S_ * HD_;
  const __bf16* kbase = kh + (size_t)bh * S_ * HD_;
  const __bf16* vbase = vt + (size_t)bh * HD_ * S_;

  // Q as B-frags: B[n=q=lane&31][k=16ks+8*half+j]
  bf16x8 aq[4];
#pragma unroll
  for (int ks = 0; ks < 4; ++ks)
    aq[ks] = *(const bf16x8*)(qbase +
        (size_t)(q0w + q31) * HD_ + ks * 16 + half * 8);

  f32x16 o[2] = {};       // [hdt] O^T accumulators (AGPR)
  f32x2 ls = {0.f, 0.f};  // softmax denominator partials

  const int srow = t >> 3;                  // 0..31
  const int sgc = (t & 7) ^ (srow & 7);     // swizzled global chunk

  // running per-lane staging pointers, advanced by constant strides per tile
  const __bf16* kp  = kbase + (size_t)(kc * 1024 + srow) * HD_ + sgc * 8;
  const __bf16* kp2 = kp + 32 * HD_;
  const __bf16* vp  = vbase + (size_t)srow * S_ + kc * 1024 + sgc * 8;
  const __bf16* vp2 = vp + 32 * S_;
  char* lk0 = (char*)&lK[0][0] + t * 16;
  char* lv0 = (char*)&lV[0][0] + t * 16;

  auto stage = [&](int buf) {
    char* lk = lk0 + (buf << 13);
    char* lv = lv0 + (buf << 13);
    gload16(kp,  lk);
    gload16(kp2, lk + 4096);
    gload16(vp,  lv);
    gload16(vp2, lv + 4096);
    kp += 64 * HD_; kp2 += 64 * HD_;
    vp += 64;       vp2 += 64;
  };

  stage(0);

#pragma unroll 2
  for (int kt0 = 0; kt0 < 16; ++kt0) {
    const int cur = kt0 & 1;
    __syncthreads();  // buf[cur] staged; all waves done reading buf[cur^1]
    if (kt0 + 1 < 16) stage(cur ^ 1);

#pragma unroll
    for (int st = 0; st < 2; ++st) {
      // K-frags for this 32-key sub-tile
      bf16x8 fk[4];
      const int row = st * 32 + q31;
#pragma unroll
      for (int ks = 0; ks < 4; ++ks) {
        int pos = (2 * ks + half) ^ (q31 & 7);
        fk[ks] = *(const bf16x8*)((const char*)&lK[cur][0] + row * 128 + pos * 16);
      }

      // S^T = K·Q^T
      f32x16 sc = {};
#pragma unroll
      for (int ks = 0; ks < 4; ++ks)
        sc = __builtin_amdgcn_mfma_f32_32x32x16_bf16(fk[ks], aq[ks], sc, 0, 0, 0);

      // V^T-frags (issued here so their latency hides under the QK chain)
      s16x4 fv[2][4];  // [hdt][g]
#pragma unroll
      for (int hdt = 0; hdt < 2; ++hdt) {
        const int rowv = hdt * 32 + q31;
#pragma unroll
        for (int g = 0; g < 4; ++g) {
          int pos = (4 * st + g) ^ (q31 & 7);
          fv[hdt][g] = *(const s16x4*)((const char*)&lV[cur][0] + rowv * 128 +
                                       pos * 16 + half * 8);
        }
      }

      // exp2 + packed lsum + pack pairs via v_perm (round-half-up)
      uint32_t pk[8];
#pragma unroll
      for (int p = 0; p < 8; ++p) {
        float ea = __builtin_amdgcn_exp2f(sc[2 * p]);
        float eb = __builtin_amdgcn_exp2f(sc[2 * p + 1]);
        f32x2 e2 = {ea, eb};
        ls += e2;
        uint32_t au = __builtin_bit_cast(uint32_t, ea) + 0x8000u;
        uint32_t bu = __builtin_bit_cast(uint32_t, eb) + 0x8000u;
        pk[p] = __builtin_amdgcn_perm(bu, au, 0x07060302u);
      }

      // P B-frags, K=16 (k-map k(h,j) = 8*(j>>2) + 4h + (j&3), matches fv)
      u32x4 w;
      w[0] = pk[0]; w[1] = pk[1]; w[2] = pk[2]; w[3] = pk[3];
      bf16x8 fpa = __builtin_bit_cast(bf16x8, w);
      w[0] = pk[4]; w[1] = pk[5]; w[2] = pk[6]; w[3] = pk[7];
      bf16x8 fpb = __builtin_bit_cast(bf16x8, w);

      // O^T += V^T · P^T, K=16 per MFMA
#pragma unroll
      for (int hdt = 0; hdt < 2; ++hdt) {
        bf16x8 av0 = cat8(fv[hdt][0], fv[hdt][1]);
        bf16x8 av1 = cat8(fv[hdt][2], fv[hdt][3]);
        o[hdt] = __builtin_amdgcn_mfma_f32_32x32x16_bf16(av0, fpa, o[hdt], 0, 0, 0);
        o[hdt] = __builtin_amdgcn_mfma_f32_32x32x16_bf16(av1, fpb, o[hdt], 0, 0, 0);
      }
    }
  }

  // store partials: po[(kc*32+bh)][qrow][hd] bf16 (8B per lane-row), pl fp32
  const size_t slab = (size_t)(kc * 32 + bh) * S_;
  float lq = ls.x + ls.y;
  float ltot = lq + __shfl_xor(lq, 32);
  const int qrow = q0w + q31;
  if (half == 0) pl[slab + qrow] = ltot;
#pragma unroll
  for (int hdt = 0; hdt < 2; ++hdt)
#pragma unroll
    for (int rq = 0; rq < 4; ++rq) {
      bf16x4 pk4;
      pk4[0] = (__bf16)o[hdt][rq * 4 + 0];
      pk4[1] = (__bf16)o[hdt][rq * 4 + 1];
      pk4[2] = (__bf16)o[hdt][rq * 4 + 2];
      pk4[3] = (__bf16)o[hdt][rq * 4 + 3];
      *(bf16x4*)(po + (slab + qrow) * HD_ + hdt * 32 + rq * 8 + half * 4) = pk4;
    }
}

// ---------------- attention phase 2: combine, divide, mean-pool ----------------
// grid (rg=32, bh=32) = 1024 blocks (4/CU). Each block: 64 rows x 2 slabs.
__global__ __launch_bounds__(256) void attn2(const __bf16* __restrict__ po,
                                             const float* __restrict__ pl,
                                             float* __restrict__ out) {
  __shared__ float red[256];
  const int t = threadIdx.x;
  const int hd = t & 63;
  const int rgrp = t >> 6;
  const int bh = blockIdx.y;
  const int r0 = blockIdx.x * 64 + rgrp * 16;
  const size_t s0 = (size_t)bh * S_;
  const size_t s1 = (size_t)(32 + bh) * S_;
  float acc = 0.f;
#pragma unroll 4
  for (int i = 0; i < 16; ++i) {
    int row = r0 + i;
    float l = pl[s0 + row] + pl[s1 + row];
    float v = (float)po[(s0 + row) * HD_ + hd] +
              (float)po[(s1 + row) * HD_ + hd];
    acc += v / l;
  }
  red[t] = acc;
  __syncthreads();
  if (t < 64) {
    float s = red[t] + red[t + 64] + red[t + 128] + red[t + 192];
    atomicAdd(out + (size_t)(bh >> 4) * D_ + (bh & 15) * HD_ + hd,
              s * (1.0f / S_));
  }
}

extern "C" void kernel_launch(void* const* d_in, const int* in_sizes, int n_in,
                              void* d_out, int out_size, void* d_ws, size_t ws_size,
                              hipStream_t stream) {
  const float* x  = (const float*)d_in[0];
  const float* Wq = (const float*)d_in[1];
  const float* bq = (const float*)d_in[2];
  const float* Wk = (const float*)d_in[3];
  const float* bk = (const float*)d_in[4];
  const float* Wv = (const float*)d_in[5];
  const float* bv = (const float*)d_in[6];
  float* out = (float*)d_out;

  char* ws = (char*)d_ws;
  __bf16* qh = (__bf16*)(ws);                       //  0..8 MB
  __bf16* kh = (__bf16*)(ws + ((size_t)8  << 20));  //  8..16 MB
  __bf16* vt = (__bf16*)(ws + ((size_t)16 << 20));  // 16..24 MB
  __bf16* xb = (__bf16*)(ws + ((size_t)24 << 20));  // 24..32 MB (dead after gemm)
  __bf16* wt = (__bf16*)(ws + ((size_t)32 << 20));  // 32..38 MB (dead after gemm)
  __bf16* po = (__bf16*)(ws + ((size_t)24 << 20));  // 24..40 MB (overlays xb/wt)
  float*  pl = (float*) (ws + ((size_t)40 << 20));  // 40..40.5 MB

  prep<<<dim3(7169), dim3(256), 0, stream>>>(x, Wq, Wk, Wv, xb, wt, out);
  gemm_qkv<<<dim3(32, 8, 3), dim3(256), 0, stream>>>(xb, wt, bq, bk, bv, qh, kh, vt);
  attn1<<<dim3(B_ * H_, 16, 2), dim3(256), 0, stream>>>(qh, kh, vt, po, pl);
  attn2<<<dim3(32, B_ * H_), dim3(256), 0, stream>>>(po, pl, out);
}

// Round 11
// 160.742 us; speedup vs baseline: 1.0357x; 1.0357x over previous
//
#include <hip/hip_runtime.h>
#include <hip/hip_bf16.h>
#include <stdint.h>

#define B_  2
#define S_  2048
#define D_  1024
#define H_  16
#define HD_ 64

typedef __attribute__((ext_vector_type(8)))  __bf16 bf16x8;
typedef __attribute__((ext_vector_type(4)))  __bf16 bf16x4;
typedef __attribute__((ext_vector_type(2)))  float  f32x2;
typedef __attribute__((ext_vector_type(4)))  float  f32x4;
typedef __attribute__((ext_vector_type(16))) float  f32x16;
typedef __attribute__((ext_vector_type(4)))  uint32_t u32x4;

// 0.125 * log2(e): folded into Q so attention scores feed exp2 directly.
#define QSCALE 0.18033688011112042f

__device__ __forceinline__ void gload16(const void* g, void* l) {
  __builtin_amdgcn_global_load_lds(
      (__attribute__((address_space(1))) void*)(uintptr_t)g,
      (__attribute__((address_space(3))) void*)(uintptr_t)l,
      16, 0, 0);
}

// NOTE (R4): v_cvt_pk_bf16_f32 packing FAILED accuracy; keep +0x8000+v_perm.
// NOTE (R6): fused butterfly/atomic epilogue failed accuracy; po/pl+attn2 is
// the proven path.
// NOTE (R8): doubling occupancy (32q/wave, 4 waves/SIMD) left dur_us unchanged
// -> attn1 is NOT TLP-latency-bound. Remaining measurable inefficiency: LDS
// bank conflicts (3.1M cyc/dispatch) from b64 V-fragment reads (4-way: 32 rows
// onto 8 swizzle slots per cycle). R9 fixes this by storing vt in FRAGMENT
// ORDER (gemm z=2 bit-swaps the low 2 bits of each 8B-run index within every
// 64-sk block) so PV A-operands are single b128 reads (16 lanes/cycle -> 2
// rows/slot -> conflict-free), bit-identical arithmetic.
// NOTE (R9/R10): bench infra failed twice at container acquisition (broker
// error, pre-compile) - kernel resubmitted verbatim, theory still untested.

// ---------------- fused prep: zero out / convert X / transpose W ----------------
__global__ __launch_bounds__(256) void prep(
    const float* __restrict__ x, const float* __restrict__ wq,
    const float* __restrict__ wk, const float* __restrict__ wv,
    __bf16* __restrict__ xb, __bf16* __restrict__ wt, float* __restrict__ out) {
  __shared__ float tile[32][33];
  const int t = threadIdx.x;
  const int bx = blockIdx.x;
  if (bx < 4096) {
    int i = bx * 256 + t;
    float4 v = ((const float4*)x)[i];
    bf16x4 o;
    o[0] = (__bf16)v.x; o[1] = (__bf16)v.y; o[2] = (__bf16)v.z; o[3] = (__bf16)v.w;
    ((bf16x4*)xb)[i] = o;
  } else if (bx < 7168) {
    int tb = bx - 4096;
    int z = tb >> 10;
    int rem = tb & 1023;
    int n0 = (rem & 31) * 32, k0 = (rem >> 5) * 32;
    const float* w = (z == 0) ? wq : (z == 1 ? wk : wv);
    __bf16* o = wt + (size_t)z * D_ * D_;
    int tx = t & 31, ty = t >> 5;
    for (int i = 0; i < 4; ++i)
      tile[ty + 8 * i][tx] = w[(size_t)(k0 + ty + 8 * i) * D_ + n0 + tx];
    __syncthreads();
    for (int i = 0; i < 4; ++i)
      o[(size_t)(n0 + ty + 8 * i) * D_ + k0 + tx] = (__bf16)tile[tx][ty + 8 * i];
  } else {
    float4* o4 = (float4*)out;
    float4 z4 = {0.f, 0.f, 0.f, 0.f};
    o4[t] = z4;
    o4[t + 256] = z4;
  }
}

// ---------------- QKV GEMM, 128x128, BK=32, dbuf ----------------
// R9 change: z=2 (V^T) store address uses the low-2-bit-swapped run index so
// vt is laid out in attn1's PV-fragment order (values unchanged, 8B runs
// relocated within each 64-sk block; swap is an involution).
__global__ __launch_bounds__(256, 3) void gemm_qkv(
    const __bf16* __restrict__ xb, const __bf16* __restrict__ wt,
    const float* __restrict__ bq, const float* __restrict__ bk,
    const float* __restrict__ bv, __bf16* __restrict__ qh,
    __bf16* __restrict__ kh, __bf16* __restrict__ vt) {
  constexpr int K = 1024;
  constexpr int NIT = K / 32;
  __shared__ __attribute__((aligned(16))) __bf16 lA[2][128 * 32];
  __shared__ __attribute__((aligned(16))) __bf16 lB[2][128 * 32];

  const int z = blockIdx.z;
  const __bf16* w = wt + (size_t)z * K * D_;
  const float* bias = (z == 0) ? bq : (z == 1 ? bk : bv);
  const int t = threadIdx.x;
  const int lane = t & 63;
  const int wid = t >> 6;
  const int quad = lane >> 4;
  const int col = lane & 15;
  const int m0 = blockIdx.x * 128;
  const int n0 = blockIdx.y * 128;
  const int wr = (wid >> 1) * 64;
  const int wc = (wid & 1) * 64;

  const int sr0 = t >> 2;
  const int gc = (t & 3) ^ ((t >> 2) & 3);

  auto stage = [&](int kt, int buf) {
    gload16(xb + (size_t)(m0 + sr0) * K + kt * 32 + gc * 8,
            (char*)&lA[buf][0] + t * 16);
    gload16(xb + (size_t)(m0 + 64 + sr0) * K + kt * 32 + gc * 8,
            (char*)&lA[buf][0] + 4096 + t * 16);
    gload16(w + (size_t)(n0 + sr0) * K + kt * 32 + gc * 8,
            (char*)&lB[buf][0] + t * 16);
    gload16(w + (size_t)(n0 + 64 + sr0) * K + kt * 32 + gc * 8,
            (char*)&lB[buf][0] + 4096 + t * 16);
  };

  f32x4 acc[4][4] = {};

  stage(0, 0);

  if (z < 2) {
    for (int kt = 0; kt < NIT; ++kt) {
      const int cur = kt & 1;
      __syncthreads();
      if (kt + 1 < NIT) stage(kt + 1, cur ^ 1);
      bf16x8 fw[4], fx[4];
      for (int i = 0; i < 4; ++i) {
        int n = wr + i * 16 + col;
        int sl = quad ^ (n & 3);
        fw[i] = *(const bf16x8*)((const char*)&lB[cur][0] + n * 64 + sl * 16);
      }
      for (int j = 0; j < 4; ++j) {
        int m = wc + j * 16 + col;
        int sl = quad ^ (m & 3);
        fx[j] = *(const bf16x8*)((const char*)&lA[cur][0] + m * 64 + sl * 16);
      }
      for (int i = 0; i < 4; ++i)
        for (int j = 0; j < 4; ++j)
          acc[i][j] = __builtin_amdgcn_mfma_f32_16x16x32_bf16(
              fw[i], fx[j], acc[i][j], 0, 0, 0);
    }
    const float scale = (z == 0) ? QSCALE : 1.0f;
    __bf16* dst = (z == 0) ? qh : kh;
    for (int i = 0; i < 4; ++i) {
      int gnb = n0 + wr + i * 16 + quad * 4;
      float4 bi = *(const float4*)(bias + gnb);
      int h = gnb >> 6, hd = gnb & 63;
      for (int j = 0; j < 4; ++j) {
        int gm = m0 + wc + j * 16 + col;
        int b = gm >> 11, s = gm & 2047;
        bf16x4 pk;
        pk[0] = (__bf16)((acc[i][j][0] + bi.x) * scale);
        pk[1] = (__bf16)((acc[i][j][1] + bi.y) * scale);
        pk[2] = (__bf16)((acc[i][j][2] + bi.z) * scale);
        pk[3] = (__bf16)((acc[i][j][3] + bi.w) * scale);
        *(bf16x4*)(dst + ((size_t)(b * H_ + h) * S_ + s) * HD_ + hd) = pk;
      }
    }
  } else {
    for (int kt = 0; kt < NIT; ++kt) {
      const int cur = kt & 1;
      __syncthreads();
      if (kt + 1 < NIT) stage(kt + 1, cur ^ 1);
      bf16x8 fx[4], fw[4];
      for (int i = 0; i < 4; ++i) {
        int m = wr + i * 16 + col;
        int sl = quad ^ (m & 3);
        fx[i] = *(const bf16x8*)((const char*)&lA[cur][0] + m * 64 + sl * 16);
      }
      for (int j = 0; j < 4; ++j) {
        int n = wc + j * 16 + col;
        int sl = quad ^ (n & 3);
        fw[j] = *(const bf16x8*)((const char*)&lB[cur][0] + n * 64 + sl * 16);
      }
      for (int i = 0; i < 4; ++i)
        for (int j = 0; j < 4; ++j)
          acc[i][j] = __builtin_amdgcn_mfma_f32_16x16x32_bf16(
              fx[i], fw[j], acc[i][j], 0, 0, 0);
    }
    // fragment-order store: run index rho = i*4+quad within each 64-s block;
    // store run at slot rho' = swap(low 2 bits of rho) -> quad' = swap2(quad).
    const int quadv = ((quad & 1) << 1) | ((quad >> 1) & 1);
    for (int i = 0; i < 4; ++i) {
      int gmb = m0 + wr + i * 16 + quad * 4;    // value rows (batch index)
      int gms = m0 + wr + i * 16 + quadv * 4;   // store slot (frag order)
      int b = gmb >> 11, s = gms & 2047;
      for (int j = 0; j < 4; ++j) {
        int gn = n0 + wc + j * 16 + col;
        int h = gn >> 6, hd = gn & 63;
        float bi = bias[gn];
        bf16x4 pk;
        pk[0] = (__bf16)(acc[i][j][0] + bi);
        pk[1] = (__bf16)(acc[i][j][1] + bi);
        pk[2] = (__bf16)(acc[i][j][2] + bi);
        pk[3] = (__bf16)(acc[i][j][3] + bi);
        *(bf16x4*)(vt + ((size_t)(b * H_ + h) * HD_ + hd) * S_ + s) = pk;
      }
    }
  }
}

// ---------------- attention phase 1: 64 q/wave, b128 V-fragment reads ----------------
// grid (bh=32, qblk=8, kc=2) = 512 blocks = 2/CU; XCD = bh%8.
// R9 = R2 structure with PV A-operands read as single b128 from the
// fragment-ordered vt (see gemm): 16 b64 (4-way conflicted) -> 8 b128
// (conflict-free), cat8 concat deleted. Bit-identical arithmetic vs R2.
// NOTE (R1): never cap regs at 128 (spill -> 3GB/disp scratch streamer).
// NOTE (R3): KSTEP=128 / setprio neutral-to-negative. (R5): VALU-count cut
// neutral. (R7): explicit SW pipeline neutral. (R8): 2x occupancy neutral.
__global__ __launch_bounds__(256, 2) void attn1(
    const __bf16* __restrict__ qh, const __bf16* __restrict__ kh,
    const __bf16* __restrict__ vt, __bf16* __restrict__ po,
    float* __restrict__ pl) {
  __shared__ __attribute__((aligned(16))) __bf16 lK[2][64 * 64];  // [sk][hd] swz
  __shared__ __attribute__((aligned(16))) __bf16 lV[2][64 * 64];  // [hd][sk-frag] swz

  const int t = threadIdx.x;
  const int lane = t & 63;
  const int half = lane >> 5;
  const int q31 = lane & 31;
  const int bh = blockIdx.x;
  const int kc = blockIdx.z;
  const int q0w = blockIdx.y * 256 + (t >> 6) * 64;  // wave's 64 q rows

  const __bf16* qbase = qh + (size_t)bh * S_ * HD_;
  const __bf16* kbase = kh + (size_t)bh * S_ * HD_;
  const __bf16* vbase = vt + (size_t)bh * HD_ * S_;

  // Q as B-frags: B[n=q=lane&31][k=16ks+8*half+j], per q-tile
  bf16x8 aq[2][4];
  for (int qt = 0; qt < 2; ++qt)
    for (int ks = 0; ks < 4; ++ks)
      aq[qt][ks] = *(const bf16x8*)(qbase +
          (size_t)(q0w + qt * 32 + q31) * HD_ + ks * 16 + half * 8);

  f32x16 o[2][2] = {};  // [qt][hdt]
  f32x2 ls[2] = {{0.f, 0.f}, {0.f, 0.f}};

  const int srow = t >> 3;                  // 0..31
  const int sgc = (t & 7) ^ (srow & 7);     // swizzled global chunk

  auto stage = [&](int kt, int buf) {
    gload16(kbase + (size_t)(kt * 64 + srow) * HD_ + sgc * 8,
            (char*)&lK[buf][0] + t * 16);
    gload16(kbase + (size_t)(kt * 64 + 32 + srow) * HD_ + sgc * 8,
            (char*)&lK[buf][0] + 4096 + t * 16);
    gload16(vbase + (size_t)srow * S_ + kt * 64 + sgc * 8,
            (char*)&lV[buf][0] + t * 16);
    gload16(vbase + (size_t)(32 + srow) * S_ + kt * 64 + sgc * 8,
            (char*)&lV[buf][0] + 4096 + t * 16);
  };

  stage(kc * 16, 0);

  for (int kt0 = 0; kt0 < 16; ++kt0) {
    const int cur = kt0 & 1;
    __syncthreads();  // drains vmcnt: buf[cur] staged; all done reading buf[cur^1]
    if (kt0 + 1 < 16) stage(kc * 16 + kt0 + 1, cur ^ 1);

    // ---- hoisted LDS reads: everything this iteration needs ----
    bf16x8 fk[2][4];       // [st][ks]
    bf16x8 av[2][2][2];    // [st][hdt][k2] V^T A-frags (b128, frag-ordered vt)
#pragma unroll
    for (int st = 0; st < 2; ++st) {
      const int row = st * 32 + q31;
#pragma unroll
      for (int ks = 0; ks < 4; ++ks) {
        int pos = (2 * ks + half) ^ (row & 7);
        fk[st][ks] = *(const bf16x8*)((const char*)&lK[cur][0] + row * 128 + pos * 16);
      }
    }
#pragma unroll
    for (int st = 0; st < 2; ++st)
#pragma unroll
      for (int hdt = 0; hdt < 2; ++hdt) {
        const int rowv = hdt * 32 + q31;
#pragma unroll
        for (int k2 = 0; k2 < 2; ++k2) {
          int pos = (st * 4 + k2 * 2 + half) ^ (rowv & 7);
          av[st][hdt][k2] = *(const bf16x8*)((const char*)&lV[cur][0] + rowv * 128 +
                                             pos * 16);
        }
      }

#pragma unroll
    for (int st = 0; st < 2; ++st) {
      // S^T tiles for both q-tiles; each fk feeds two MFMAs
      f32x16 sc0 = {}, sc1 = {};
#pragma unroll
      for (int ks = 0; ks < 4; ++ks) {
        sc0 = __builtin_amdgcn_mfma_f32_32x32x16_bf16(fk[st][ks], aq[0][ks], sc0, 0, 0, 0);
        sc1 = __builtin_amdgcn_mfma_f32_32x32x16_bf16(fk[st][ks], aq[1][ks], sc1, 0, 0, 0);
      }

      // exp2 + packed lsum + pack pairs via v_perm (round-half-up), per q-tile
      uint32_t pk0[8], pk1[8];
#pragma unroll
      for (int p = 0; p < 8; ++p) {
        float ea = __builtin_amdgcn_exp2f(sc0[2 * p]);
        float eb = __builtin_amdgcn_exp2f(sc0[2 * p + 1]);
        f32x2 e2 = {ea, eb};
        ls[0] += e2;
        uint32_t au = __builtin_bit_cast(uint32_t, ea) + 0x8000u;
        uint32_t bu = __builtin_bit_cast(uint32_t, eb) + 0x8000u;
        pk0[p] = __builtin_amdgcn_perm(bu, au, 0x07060302u);
      }
#pragma unroll
      for (int p = 0; p < 8; ++p) {
        float ea = __builtin_amdgcn_exp2f(sc1[2 * p]);
        float eb = __builtin_amdgcn_exp2f(sc1[2 * p + 1]);
        f32x2 e2 = {ea, eb};
        ls[1] += e2;
        uint32_t au = __builtin_bit_cast(uint32_t, ea) + 0x8000u;
        uint32_t bu = __builtin_bit_cast(uint32_t, eb) + 0x8000u;
        pk1[p] = __builtin_amdgcn_perm(bu, au, 0x07060302u);
      }

      // P B-frags, K=16 (k-map k(h,j) = 8*(j>>2) + 4h + (j&3), matches av)
      u32x4 w;
      w[0] = pk0[0]; w[1] = pk0[1]; w[2] = pk0[2]; w[3] = pk0[3];
      bf16x8 fp0a = __builtin_bit_cast(bf16x8, w);
      w[0] = pk0[4]; w[1] = pk0[5]; w[2] = pk0[6]; w[3] = pk0[7];
      bf16x8 fp0b = __builtin_bit_cast(bf16x8, w);
      w[0] = pk1[0]; w[1] = pk1[1]; w[2] = pk1[2]; w[3] = pk1[3];
      bf16x8 fp1a = __builtin_bit_cast(bf16x8, w);
      w[0] = pk1[4]; w[1] = pk1[5]; w[2] = pk1[6]; w[3] = pk1[7];
      bf16x8 fp1b = __builtin_bit_cast(bf16x8, w);

      // O^T += V^T · P^T, K=16 per MFMA (av read directly from LDS, no concat)
#pragma unroll
      for (int hdt = 0; hdt < 2; ++hdt) {
        o[0][hdt] = __builtin_amdgcn_mfma_f32_32x32x16_bf16(av[st][hdt][0], fp0a, o[0][hdt], 0, 0, 0);
        o[1][hdt] = __builtin_amdgcn_mfma_f32_32x32x16_bf16(av[st][hdt][0], fp1a, o[1][hdt], 0, 0, 0);
        o[0][hdt] = __builtin_amdgcn_mfma_f32_32x32x16_bf16(av[st][hdt][1], fp0b, o[0][hdt], 0, 0, 0);
        o[1][hdt] = __builtin_amdgcn_mfma_f32_32x32x16_bf16(av[st][hdt][1], fp1b, o[1][hdt], 0, 0, 0);
      }
    }
  }

  // store partials per q-tile: po[(kc*32+bh)][qrow][hd] bf16 (8B), pl fp32
  const size_t slab = (size_t)(kc * 32 + bh) * S_;
  for (int qt = 0; qt < 2; ++qt) {
    float lq = ls[qt].x + ls[qt].y;
    float ltot = lq + __shfl_xor(lq, 32);
    const int qrow = q0w + qt * 32 + q31;
    if (half == 0) pl[slab + qrow] = ltot;
    for (int hdt = 0; hdt < 2; ++hdt)
      for (int rq = 0; rq < 4; ++rq) {
        bf16x4 pk;
        pk[0] = (__bf16)o[qt][hdt][rq * 4 + 0];
        pk[1] = (__bf16)o[qt][hdt][rq * 4 + 1];
        pk[2] = (__bf16)o[qt][hdt][rq * 4 + 2];
        pk[3] = (__bf16)o[qt][hdt][rq * 4 + 3];
        *(bf16x4*)(po + (slab + qrow) * HD_ + hdt * 32 + rq * 8 + half * 4) = pk;
      }
  }
}

// ---------------- attention phase 2: combine, divide, mean-pool ----------------
// grid (rg=32, bh=32) = 1024 blocks (4/CU). Each block: 64 rows x 2 slabs.
__global__ __launch_bounds__(256) void attn2(const __bf16* __restrict__ po,
                                             const float* __restrict__ pl,
                                             float* __restrict__ out) {
  __shared__ float red[256];
  const int t = threadIdx.x;
  const int hd = t & 63;
  const int rgrp = t >> 6;
  const int bh = blockIdx.y;
  const int r0 = blockIdx.x * 64 + rgrp * 16;
  const size_t s0 = (size_t)bh * S_;
  const size_t s1 = (size_t)(32 + bh) * S_;
  float acc = 0.f;
#pragma unroll 4
  for (int i = 0; i < 16; ++i) {
    int row = r0 + i;
    float l = pl[s0 + row] + pl[s1 + row];
    float v = (float)po[(s0 + row) * HD_ + hd] +
              (float)po[(s1 + row) * HD_ + hd];
    acc += v / l;
  }
  red[t] = acc;
  __syncthreads();
  if (t < 64) {
    float s = red[t] + red[t + 64] + red[t + 128] + red[t + 192];
    atomicAdd(out + (size_t)(bh >> 4) * D_ + (bh & 15) * HD_ + hd,
              s * (1.0f / S_));
  }
}

extern "C" void kernel_launch(void* const* d_in, const int* in_sizes, int n_in,
                              void* d_out, int out_size, void* d_ws, size_t ws_size,
                              hipStream_t stream) {
  const float* x  = (const float*)d_in[0];
  const float* Wq = (const float*)d_in[1];
  const float* bq = (const float*)d_in[2];
  const float* Wk = (const float*)d_in[3];
  const float* bk = (const float*)d_in[4];
  const float* Wv = (const float*)d_in[5];
  const float* bv = (const float*)d_in[6];
  float* out = (float*)d_out;

  char* ws = (char*)d_ws;
  __bf16* qh = (__bf16*)(ws);                       //  0..8 MB
  __bf16* kh = (__bf16*)(ws + ((size_t)8  << 20));  //  8..16 MB
  __bf16* vt = (__bf16*)(ws + ((size_t)16 << 20));  // 16..24 MB
  __bf16* xb = (__bf16*)(ws + ((size_t)24 << 20));  // 24..32 MB (dead after gemm)
  __bf16* wt = (__bf16*)(ws + ((size_t)32 << 20));  // 32..38 MB (dead after gemm)
  __bf16* po = (__bf16*)(ws + ((size_t)24 << 20));  // 24..40 MB (overlays xb/wt)
  float*  pl = (float*) (ws + ((size_t)40 << 20));  // 40..40.5 MB

  prep<<<dim3(7169), dim3(256), 0, stream>>>(x, Wq, Wk, Wv, xb, wt, out);
  gemm_qkv<<<dim3(32, 8, 3), dim3(256), 0, stream>>>(xb, wt, bq, bk, bv, qh, kh, vt);
  attn1<<<dim3(B_ * H_, 8, 2), dim3(256), 0, stream>>>(qh, kh, vt, po, pl);
  attn2<<<dim3(32, B_ * H_), dim3(256), 0, stream>>>(po, pl, out);
}

// Round 12
// 157.756 us; speedup vs baseline: 1.0553x; 1.0189x over previous
//
#include <hip/hip_runtime.h>
#include <hip/hip_bf16.h>
#include <stdint.h>

#define B_  2
#define S_  2048
#define D_  1024
#define H_  16
#define HD_ 64

typedef __attribute__((ext_vector_type(8)))  __bf16 bf16x8;
typedef __attribute__((ext_vector_type(4)))  __bf16 bf16x4;
typedef __attribute__((ext_vector_type(2)))  float  f32x2;
typedef __attribute__((ext_vector_type(4)))  float  f32x4;
typedef __attribute__((ext_vector_type(16))) float  f32x16;
typedef __attribute__((ext_vector_type(4)))  uint32_t u32x4;

// 0.125 * log2(e): folded into Q so attention scores feed exp2 directly.
#define QSCALE 0.18033688011112042f

__device__ __forceinline__ void gload16(const void* g, void* l) {
  __builtin_amdgcn_global_load_lds(
      (__attribute__((address_space(1))) void*)(uintptr_t)g,
      (__attribute__((address_space(3))) void*)(uintptr_t)l,
      16, 0, 0);
}

// NOTE (R4): v_cvt_pk_bf16_f32 packing FAILED accuracy; keep +0x8000+v_perm.
// NOTE (R6): fused butterfly/atomic epilogue failed accuracy; po/pl+attn2 is
// the proven path.
// NOTE (R8): 2x occupancy neutral -> attn1 not TLP-bound.
// NOTE (R11): fragment-order vt + b128 V-frag reads VERIFIED: conflicts
// 3.1M->2.1M, attn1 47.5->45.4 us, absmax unchanged. Keep.
// NOTE (R12): accounting -> gemm_qkv ~40-44 us (co-leader; never in top-5 so
// <45.3, and prep/attn2 traffic-bound ~10/8). Its epilogue does 16 scattered
// 8B stores/thread (128B..4KB lane stride). This round: LDS re-stage epilogue
// -> contiguous 128B/256B row writes. Values & addresses identical.

// ---------------- fused prep: zero out / convert X / transpose W ----------------
__global__ __launch_bounds__(256) void prep(
    const float* __restrict__ x, const float* __restrict__ wq,
    const float* __restrict__ wk, const float* __restrict__ wv,
    __bf16* __restrict__ xb, __bf16* __restrict__ wt, float* __restrict__ out) {
  __shared__ float tile[32][33];
  const int t = threadIdx.x;
  const int bx = blockIdx.x;
  if (bx < 4096) {
    int i = bx * 256 + t;
    float4 v = ((const float4*)x)[i];
    bf16x4 o;
    o[0] = (__bf16)v.x; o[1] = (__bf16)v.y; o[2] = (__bf16)v.z; o[3] = (__bf16)v.w;
    ((bf16x4*)xb)[i] = o;
  } else if (bx < 7168) {
    int tb = bx - 4096;
    int z = tb >> 10;
    int rem = tb & 1023;
    int n0 = (rem & 31) * 32, k0 = (rem >> 5) * 32;
    const float* w = (z == 0) ? wq : (z == 1 ? wk : wv);
    __bf16* o = wt + (size_t)z * D_ * D_;
    int tx = t & 31, ty = t >> 5;
    for (int i = 0; i < 4; ++i)
      tile[ty + 8 * i][tx] = w[(size_t)(k0 + ty + 8 * i) * D_ + n0 + tx];
    __syncthreads();
    for (int i = 0; i < 4; ++i)
      o[(size_t)(n0 + ty + 8 * i) * D_ + k0 + tx] = (__bf16)tile[tx][ty + 8 * i];
  } else {
    float4* o4 = (float4*)out;
    float4 z4 = {0.f, 0.f, 0.f, 0.f};
    o4[t] = z4;
    o4[t + 256] = z4;
  }
}

// ---------------- QKV GEMM, 128x128, BK=32, dbuf; coalesced epilogue ----------------
// R12: main loop unchanged (LDS carved from one pool). Epilogue: acc -> LDS
// tile [128][PITCH=136] bf16 (272B pitch: b128-aligned, store<=4-way cheap,
// read 2-way free), barrier, re-read so each 16-lane group writes a full
// contiguous output row (qh/kh: 128B rows; vt: 256B rows). vt keeps R9's
// fragment-order slot permutation (quadv).
__global__ __launch_bounds__(256, 3) void gemm_qkv(
    const __bf16* __restrict__ xb, const __bf16* __restrict__ wt,
    const float* __restrict__ bq, const float* __restrict__ bk,
    const float* __restrict__ bv, __bf16* __restrict__ qh,
    __bf16* __restrict__ kh, __bf16* __restrict__ vt) {
  constexpr int K = 1024;
  constexpr int NIT = K / 32;
  constexpr int PITCH = 136;  // elems; 272B rows, 16B-aligned
  __shared__ __attribute__((aligned(16))) char smem[34816];
  auto lA = [&](int buf) -> char* { return smem + buf * 8192; };
  auto lB = [&](int buf) -> char* { return smem + 16384 + buf * 8192; };
  __bf16* epi = (__bf16*)smem;  // epilogue tile, reused after final barrier

  const int z = blockIdx.z;
  const __bf16* w = wt + (size_t)z * K * D_;
  const float* bias = (z == 0) ? bq : (z == 1 ? bk : bv);
  const int t = threadIdx.x;
  const int lane = t & 63;
  const int wid = t >> 6;
  const int quad = lane >> 4;
  const int col = lane & 15;
  const int m0 = blockIdx.x * 128;
  const int n0 = blockIdx.y * 128;
  const int wr = (wid >> 1) * 64;
  const int wc = (wid & 1) * 64;

  const int sr0 = t >> 2;
  const int gc = (t & 3) ^ ((t >> 2) & 3);

  auto stage = [&](int kt, int buf) {
    gload16(xb + (size_t)(m0 + sr0) * K + kt * 32 + gc * 8, lA(buf) + t * 16);
    gload16(xb + (size_t)(m0 + 64 + sr0) * K + kt * 32 + gc * 8,
            lA(buf) + 4096 + t * 16);
    gload16(w + (size_t)(n0 + sr0) * K + kt * 32 + gc * 8, lB(buf) + t * 16);
    gload16(w + (size_t)(n0 + 64 + sr0) * K + kt * 32 + gc * 8,
            lB(buf) + 4096 + t * 16);
  };

  f32x4 acc[4][4] = {};

  stage(0, 0);

  if (z < 2) {
    for (int kt = 0; kt < NIT; ++kt) {
      const int cur = kt & 1;
      __syncthreads();
      if (kt + 1 < NIT) stage(kt + 1, cur ^ 1);
      bf16x8 fw[4], fx[4];
      for (int i = 0; i < 4; ++i) {
        int n = wr + i * 16 + col;
        int sl = quad ^ (n & 3);
        fw[i] = *(const bf16x8*)(lB(cur) + n * 64 + sl * 16);
      }
      for (int j = 0; j < 4; ++j) {
        int m = wc + j * 16 + col;
        int sl = quad ^ (m & 3);
        fx[j] = *(const bf16x8*)(lA(cur) + m * 64 + sl * 16);
      }
      for (int i = 0; i < 4; ++i)
        for (int j = 0; j < 4; ++j)
          acc[i][j] = __builtin_amdgcn_mfma_f32_16x16x32_bf16(
              fw[i], fx[j], acc[i][j], 0, 0, 0);
    }
    // ---- epilogue: acc -> LDS [m][n], then coalesced row stores ----
    __syncthreads();  // all waves done reading lA/lB; reuse as epi
    const float scale = (z == 0) ? QSCALE : 1.0f;
    for (int i = 0; i < 4; ++i) {
      int gnb = n0 + wr + i * 16 + quad * 4;
      float4 bi = *(const float4*)(bias + gnb);
      const int nl = wr + i * 16 + quad * 4;
      for (int j = 0; j < 4; ++j) {
        const int ml = wc + j * 16 + col;
        bf16x4 pk;
        pk[0] = (__bf16)((acc[i][j][0] + bi.x) * scale);
        pk[1] = (__bf16)((acc[i][j][1] + bi.y) * scale);
        pk[2] = (__bf16)((acc[i][j][2] + bi.z) * scale);
        pk[3] = (__bf16)((acc[i][j][3] + bi.w) * scale);
        *(bf16x4*)(epi + (size_t)ml * PITCH + nl) = pk;
      }
    }
    __syncthreads();
    __bf16* dst = (z == 0) ? qh : kh;
    const int b = m0 >> 11;
    const int h0 = n0 >> 6;
    const int sb = m0 & 2047;
    // 256 rows (2 heads x 128 s) of 128B; 8 lanes/row -> 8 rows/instruction.
    for (int k = 0; k < 8; ++k) {
      int g = k * 32 + (t >> 3);
      int h2 = g >> 7, sl2 = g & 127;
      int c = t & 7;
      bf16x8 v = *(const bf16x8*)(epi + (size_t)sl2 * PITCH + h2 * 64 + c * 8);
      *(bf16x8*)(dst + ((size_t)(b * H_ + h0 + h2) * S_ + sb + sl2) * HD_ +
                 c * 8) = v;
    }
  } else {
    for (int kt = 0; kt < NIT; ++kt) {
      const int cur = kt & 1;
      __syncthreads();
      if (kt + 1 < NIT) stage(kt + 1, cur ^ 1);
      bf16x8 fx[4], fw[4];
      for (int i = 0; i < 4; ++i) {
        int m = wr + i * 16 + col;
        int sl = quad ^ (m & 3);
        fx[i] = *(const bf16x8*)(lA(cur) + m * 64 + sl * 16);
      }
      for (int j = 0; j < 4; ++j) {
        int n = wc + j * 16 + col;
        int sl = quad ^ (n & 3);
        fw[j] = *(const bf16x8*)(lB(cur) + n * 64 + sl * 16);
      }
      for (int i = 0; i < 4; ++i)
        for (int j = 0; j < 4; ++j)
          acc[i][j] = __builtin_amdgcn_mfma_f32_16x16x32_bf16(
              fx[i], fw[j], acc[i][j], 0, 0, 0);
    }
    // ---- epilogue: acc -> LDS [n][m] in R9 fragment order, coalesced stores ----
    __syncthreads();
    const int quadv = ((quad & 1) << 1) | ((quad >> 1) & 1);  // R9 involution
    for (int i = 0; i < 4; ++i) {
      const int ml = wr + i * 16 + quadv * 4;  // fragment-order m slot
      for (int j = 0; j < 4; ++j) {
        int gn = n0 + wc + j * 16 + col;
        const int nl = wc + j * 16 + col;
        float bi = bias[gn];
        bf16x4 pk;
        pk[0] = (__bf16)(acc[i][j][0] + bi);
        pk[1] = (__bf16)(acc[i][j][1] + bi);
        pk[2] = (__bf16)(acc[i][j][2] + bi);
        pk[3] = (__bf16)(acc[i][j][3] + bi);
        *(bf16x4*)(epi + (size_t)nl * PITCH + ml) = pk;
      }
    }
    __syncthreads();
    const int b = m0 >> 11;
    const int sb = m0 & 2047;
    // 128 rows ((h,hd) pairs) of 256B; 16 lanes/row -> 4 rows/instruction.
    for (int k = 0; k < 8; ++k) {
      int nl = k * 16 + (t >> 4);
      int c = t & 15;
      bf16x8 v = *(const bf16x8*)(epi + (size_t)nl * PITCH + c * 8);
      int h = (n0 + nl) >> 6, hd = (n0 + nl) & 63;
      *(bf16x8*)(vt + ((size_t)(b * H_ + h) * HD_ + hd) * S_ + sb + c * 8) = v;
    }
  }
}

// ---------------- attention phase 1: 64 q/wave, b128 V-fragment reads ----------------
// grid (bh=32, qblk=8, kc=2) = 512 blocks = 2/CU; XCD = bh%8.
// R11-verified: fragment-ordered vt -> PV A-operands as single b128 reads
// (conflicts 3.1M->2.1M, 47.5->45.4 us). Bit-identical arithmetic vs R2.
// NOTE (R1): never cap regs at 128 (spill -> 3GB/disp scratch streamer).
// NOTE (R3): KSTEP=128 / setprio neutral-to-negative. (R5): VALU-count cut
// neutral. (R7): explicit SW pipeline neutral. (R8): 2x occupancy neutral.
__global__ __launch_bounds__(256, 2) void attn1(
    const __bf16* __restrict__ qh, const __bf16* __restrict__ kh,
    const __bf16* __restrict__ vt, __bf16* __restrict__ po,
    float* __restrict__ pl) {
  __shared__ __attribute__((aligned(16))) __bf16 lK[2][64 * 64];  // [sk][hd] swz
  __shared__ __attribute__((aligned(16))) __bf16 lV[2][64 * 64];  // [hd][sk-frag] swz

  const int t = threadIdx.x;
  const int lane = t & 63;
  const int half = lane >> 5;
  const int q31 = lane & 31;
  const int bh = blockIdx.x;
  const int kc = blockIdx.z;
  const int q0w = blockIdx.y * 256 + (t >> 6) * 64;  // wave's 64 q rows

  const __bf16* qbase = qh + (size_t)bh * S_ * HD_;
  const __bf16* kbase = kh + (size_t)bh * S_ * HD_;
  const __bf16* vbase = vt + (size_t)bh * HD_ * S_;

  // Q as B-frags: B[n=q=lane&31][k=16ks+8*half+j], per q-tile
  bf16x8 aq[2][4];
  for (int qt = 0; qt < 2; ++qt)
    for (int ks = 0; ks < 4; ++ks)
      aq[qt][ks] = *(const bf16x8*)(qbase +
          (size_t)(q0w + qt * 32 + q31) * HD_ + ks * 16 + half * 8);

  f32x16 o[2][2] = {};  // [qt][hdt]
  f32x2 ls[2] = {{0.f, 0.f}, {0.f, 0.f}};

  const int srow = t >> 3;                  // 0..31
  const int sgc = (t & 7) ^ (srow & 7);     // swizzled global chunk

  auto stage = [&](int kt, int buf) {
    gload16(kbase + (size_t)(kt * 64 + srow) * HD_ + sgc * 8,
            (char*)&lK[buf][0] + t * 16);
    gload16(kbase + (size_t)(kt * 64 + 32 + srow) * HD_ + sgc * 8,
            (char*)&lK[buf][0] + 4096 + t * 16);
    gload16(vbase + (size_t)srow * S_ + kt * 64 + sgc * 8,
            (char*)&lV[buf][0] + t * 16);
    gload16(vbase + (size_t)(32 + srow) * S_ + kt * 64 + sgc * 8,
            (char*)&lV[buf][0] + 4096 + t * 16);
  };

  stage(kc * 16, 0);

  for (int kt0 = 0; kt0 < 16; ++kt0) {
    const int cur = kt0 & 1;
    __syncthreads();  // drains vmcnt: buf[cur] staged; all done reading buf[cur^1]
    if (kt0 + 1 < 16) stage(kc * 16 + kt0 + 1, cur ^ 1);

    // ---- hoisted LDS reads: everything this iteration needs ----
    bf16x8 fk[2][4];       // [st][ks]
    bf16x8 av[2][2][2];    // [st][hdt][k2] V^T A-frags (b128, frag-ordered vt)
#pragma unroll
    for (int st = 0; st < 2; ++st) {
      const int row = st * 32 + q31;
#pragma unroll
      for (int ks = 0; ks < 4; ++ks) {
        int pos = (2 * ks + half) ^ (row & 7);
        fk[st][ks] = *(const bf16x8*)((const char*)&lK[cur][0] + row * 128 + pos * 16);
      }
    }
#pragma unroll
    for (int st = 0; st < 2; ++st)
#pragma unroll
      for (int hdt = 0; hdt < 2; ++hdt) {
        const int rowv = hdt * 32 + q31;
#pragma unroll
        for (int k2 = 0; k2 < 2; ++k2) {
          int pos = (st * 4 + k2 * 2 + half) ^ (rowv & 7);
          av[st][hdt][k2] = *(const bf16x8*)((const char*)&lV[cur][0] + rowv * 128 +
                                             pos * 16);
        }
      }

#pragma unroll
    for (int st = 0; st < 2; ++st) {
      // S^T tiles for both q-tiles; each fk feeds two MFMAs
      f32x16 sc0 = {}, sc1 = {};
#pragma unroll
      for (int ks = 0; ks < 4; ++ks) {
        sc0 = __builtin_amdgcn_mfma_f32_32x32x16_bf16(fk[st][ks], aq[0][ks], sc0, 0, 0, 0);
        sc1 = __builtin_amdgcn_mfma_f32_32x32x16_bf16(fk[st][ks], aq[1][ks], sc1, 0, 0, 0);
      }

      // exp2 + packed lsum + pack pairs via v_perm (round-half-up), per q-tile
      uint32_t pk0[8], pk1[8];
#pragma unroll
      for (int p = 0; p < 8; ++p) {
        float ea = __builtin_amdgcn_exp2f(sc0[2 * p]);
        float eb = __builtin_amdgcn_exp2f(sc0[2 * p + 1]);
        f32x2 e2 = {ea, eb};
        ls[0] += e2;
        uint32_t au = __builtin_bit_cast(uint32_t, ea) + 0x8000u;
        uint32_t bu = __builtin_bit_cast(uint32_t, eb) + 0x8000u;
        pk0[p] = __builtin_amdgcn_perm(bu, au, 0x07060302u);
      }
#pragma unroll
      for (int p = 0; p < 8; ++p) {
        float ea = __builtin_amdgcn_exp2f(sc1[2 * p]);
        float eb = __builtin_amdgcn_exp2f(sc1[2 * p + 1]);
        f32x2 e2 = {ea, eb};
        ls[1] += e2;
        uint32_t au = __builtin_bit_cast(uint32_t, ea) + 0x8000u;
        uint32_t bu = __builtin_bit_cast(uint32_t, eb) + 0x8000u;
        pk1[p] = __builtin_amdgcn_perm(bu, au, 0x07060302u);
      }

      // P B-frags, K=16 (k-map k(h,j) = 8*(j>>2) + 4h + (j&3), matches av)
      u32x4 w;
      w[0] = pk0[0]; w[1] = pk0[1]; w[2] = pk0[2]; w[3] = pk0[3];
      bf16x8 fp0a = __builtin_bit_cast(bf16x8, w);
      w[0] = pk0[4]; w[1] = pk0[5]; w[2] = pk0[6]; w[3] = pk0[7];
      bf16x8 fp0b = __builtin_bit_cast(bf16x8, w);
      w[0] = pk1[0]; w[1] = pk1[1]; w[2] = pk1[2]; w[3] = pk1[3];
      bf16x8 fp1a = __builtin_bit_cast(bf16x8, w);
      w[0] = pk1[4]; w[1] = pk1[5]; w[2] = pk1[6]; w[3] = pk1[7];
      bf16x8 fp1b = __builtin_bit_cast(bf16x8, w);

      // O^T += V^T · P^T, K=16 per MFMA (av read directly from LDS, no concat)
#pragma unroll
      for (int hdt = 0; hdt < 2; ++hdt) {
        o[0][hdt] = __builtin_amdgcn_mfma_f32_32x32x16_bf16(av[st][hdt][0], fp0a, o[0][hdt], 0, 0, 0);
        o[1][hdt] = __builtin_amdgcn_mfma_f32_32x32x16_bf16(av[st][hdt][0], fp1a, o[1][hdt], 0, 0, 0);
        o[0][hdt] = __builtin_amdgcn_mfma_f32_32x32x16_bf16(av[st][hdt][1], fp0b, o[0][hdt], 0, 0, 0);
        o[1][hdt] = __builtin_amdgcn_mfma_f32_32x32x16_bf16(av[st][hdt][1], fp1b, o[1][hdt], 0, 0, 0);
      }
    }
  }

  // store partials per q-tile: po[(kc*32+bh)][qrow][hd] bf16 (8B), pl fp32
  const size_t slab = (size_t)(kc * 32 + bh) * S_;
  for (int qt = 0; qt < 2; ++qt) {
    float lq = ls[qt].x + ls[qt].y;
    float ltot = lq + __shfl_xor(lq, 32);
    const int qrow = q0w + qt * 32 + q31;
    if (half == 0) pl[slab + qrow] = ltot;
    for (int hdt = 0; hdt < 2; ++hdt)
      for (int rq = 0; rq < 4; ++rq) {
        bf16x4 pk;
        pk[0] = (__bf16)o[qt][hdt][rq * 4 + 0];
        pk[1] = (__bf16)o[qt][hdt][rq * 4 + 1];
        pk[2] = (__bf16)o[qt][hdt][rq * 4 + 2];
        pk[3] = (__bf16)o[qt][hdt][rq * 4 + 3];
        *(bf16x4*)(po + (slab + qrow) * HD_ + hdt * 32 + rq * 8 + half * 4) = pk;
      }
  }
}

// ---------------- attention phase 2: combine, divide, mean-pool ----------------
// grid (rg=32, bh=32) = 1024 blocks (4/CU). Each block: 64 rows x 2 slabs.
__global__ __launch_bounds__(256) void attn2(const __bf16* __restrict__ po,
                                             const float* __restrict__ pl,
                                             float* __restrict__ out) {
  __shared__ float red[256];
  const int t = threadIdx.x;
  const int hd = t & 63;
  const int rgrp = t >> 6;
  const int bh = blockIdx.y;
  const int r0 = blockIdx.x * 64 + rgrp * 16;
  const size_t s0 = (size_t)bh * S_;
  const size_t s1 = (size_t)(32 + bh) * S_;
  float acc = 0.f;
#pragma unroll 4
  for (int i = 0; i < 16; ++i) {
    int row = r0 + i;
    float l = pl[s0 + row] + pl[s1 + row];
    float v = (float)po[(s0 + row) * HD_ + hd] +
              (float)po[(s1 + row) * HD_ + hd];
    acc += v / l;
  }
  red[t] = acc;
  __syncthreads();
  if (t < 64) {
    float s = red[t] + red[t + 64] + red[t + 128] + red[t + 192];
    atomicAdd(out + (size_t)(bh >> 4) * D_ + (bh & 15) * HD_ + hd,
              s * (1.0f / S_));
  }
}

extern "C" void kernel_launch(void* const* d_in, const int* in_sizes, int n_in,
                              void* d_out, int out_size, void* d_ws, size_t ws_size,
                              hipStream_t stream) {
  const float* x  = (const float*)d_in[0];
  const float* Wq = (const float*)d_in[1];
  const float* bq = (const float*)d_in[2];
  const float* Wk = (const float*)d_in[3];
  const float* bk = (const float*)d_in[4];
  const float* Wv = (const float*)d_in[5];
  const float* bv = (const float*)d_in[6];
  float* out = (float*)d_out;

  char* ws = (char*)d_ws;
  __bf16* qh = (__bf16*)(ws);                       //  0..8 MB
  __bf16* kh = (__bf16*)(ws + ((size_t)8  << 20));  //  8..16 MB
  __bf16* vt = (__bf16*)(ws + ((size_t)16 << 20));  // 16..24 MB
  __bf16* xb = (__bf16*)(ws + ((size_t)24 << 20));  // 24..32 MB (dead after gemm)
  __bf16* wt = (__bf16*)(ws + ((size_t)32 << 20));  // 32..38 MB (dead after gemm)
  __bf16* po = (__bf16*)(ws + ((size_t)24 << 20));  // 24..40 MB (overlays xb/wt)
  float*  pl = (float*) (ws + ((size_t)40 << 20));  // 40..40.5 MB

  prep<<<dim3(7169), dim3(256), 0, stream>>>(x, Wq, Wk, Wv, xb, wt, out);
  gemm_qkv<<<dim3(32, 8, 3), dim3(256), 0, stream>>>(xb, wt, bq, bk, bv, qh, kh, vt);
  attn1<<<dim3(B_ * H_, 8, 2), dim3(256), 0, stream>>>(qh, kh, vt, po, pl);
  attn2<<<dim3(32, B_ * H_), dim3(256), 0, stream>>>(po, pl, out);
}